// Round 8
// baseline (178.410 us; speedup 1.0000x reference)
//
#include <hip/hip_runtime.h>

typedef float f32x4 __attribute__((ext_vector_type(4)));
typedef float f32x16 __attribute__((ext_vector_type(16)));
typedef short bf16x8 __attribute__((ext_vector_type(8)));
typedef unsigned int uint;
typedef unsigned short ushort_t;

#define EMB    512
#define NSEQ   2048
#define NBATCH 4
#define NHEAD  8
#define MROWS  (NBATCH * NSEQ)   // 8192
#define CEXP   0.06375872f       // log2(e) / sqrt(512)

// round-to-nearest-even fp32 -> bf16 (bit trick)
__device__ __forceinline__ uint f2bf(float x) {
    uint u = __builtin_bit_cast(uint, x);
    return (u + 0x7fffu + ((u >> 16) & 1u)) >> 16;
}

// async global->LDS, 16B per lane; LDS dest = wave-uniform base + lane*16
__device__ __forceinline__ void glds16(const void* g, void* l) {
    __builtin_amdgcn_global_load_lds(
        (const __attribute__((address_space(1))) uint*)g,
        (__attribute__((address_space(3))) uint*)l, 16, 0, 0);
}

// ---------------------------------------------------------------------------
// Prep: x -> bf16; Wq|Wk|Wv -> Wqkvb bf16 [1536][512]; biases concat; Wo -> bf16
// ---------------------------------------------------------------------------
__global__ __launch_bounds__(256)
void prep(const float* __restrict__ x,
          const float* __restrict__ Wq, const float* __restrict__ Wk,
          const float* __restrict__ Wv, const float* __restrict__ Wo,
          const float* __restrict__ bq, const float* __restrict__ bk,
          const float* __restrict__ bv,
          ushort_t* __restrict__ xb, ushort_t* __restrict__ Wqkvb,
          float* __restrict__ bqkv, ushort_t* __restrict__ Wob) {
    int t = blockIdx.x * 256 + threadIdx.x;   // f4-group index, 1048576 total
    {
        float4 v = ((const float4*)x)[t];
        uint2 p;
        p.x = f2bf(v.x) | (f2bf(v.y) << 16);
        p.y = f2bf(v.z) | (f2bf(v.w) << 16);
        ((uint2*)xb)[t] = p;
    }
    if (t < 65536) {   // 512*512/4 groups per weight
        float4 a = ((const float4*)Wq)[t];
        float4 b = ((const float4*)Wk)[t];
        float4 c = ((const float4*)Wv)[t];
        float4 d = ((const float4*)Wo)[t];
        uint2 p;
        p.x = f2bf(a.x) | (f2bf(a.y) << 16); p.y = f2bf(a.z) | (f2bf(a.w) << 16);
        ((uint2*)Wqkvb)[t] = p;
        p.x = f2bf(b.x) | (f2bf(b.y) << 16); p.y = f2bf(b.z) | (f2bf(b.w) << 16);
        ((uint2*)Wqkvb)[t + 65536] = p;
        p.x = f2bf(c.x) | (f2bf(c.y) << 16); p.y = f2bf(c.z) | (f2bf(c.w) << 16);
        ((uint2*)Wqkvb)[t + 131072] = p;
        p.x = f2bf(d.x) | (f2bf(d.y) << 16); p.y = f2bf(d.z) | (f2bf(d.w) << 16);
        ((uint2*)Wob)[t] = p;
    }
    if (t < 512) {
        bqkv[t] = bq[t]; bqkv[512 + t] = bk[t]; bqkv[1024 + t] = bv[t];
    }
}

// ---------------------------------------------------------------------------
// GEMM C[8192 x N] = A[8192x512]bf16 * BT[Nx512]bf16 + bias, 64x64 tile,
// R15 2-phase double-buffered K-loop (unchanged).
// R16: V epilogue (MODE 0, n0>=1024) now goes through an LDS transpose and
// stores 32B/thread contiguous in tok (was: 64-lane scattered 8B stores at
// 4KB stride -> ~8x write amplification). Values bit-identical.
// ---------------------------------------------------------------------------
template<int MODE>
__global__ __launch_bounds__(256)
void gemm64(const ushort_t* __restrict__ A, const ushort_t* __restrict__ BT,
            const float* __restrict__ bias, ushort_t* __restrict__ oQK,
            ushort_t* __restrict__ oVT, float* __restrict__ oC) {
    __shared__ __align__(16) char smem[32768];
    ushort_t (*As)[2][64][32] = (ushort_t (*)[2][64][32])smem;           // 16KB
    ushort_t (*Bs)[2][64][32] = (ushort_t (*)[2][64][32])(smem + 16384); // 16KB
    float (*ep)[68] = (float (*)[68])smem;    // Q/K + MODE1 epilogue overlay
    float (*epV)[69] = (float (*)[69])smem;   // V epilogue overlay (64x69 fp32, 17.7KB)

    const int tid = threadIdx.x, wave = tid >> 6, lane = tid & 63;
    const int m0 = blockIdx.x * 64, n0 = blockIdx.y * 64;
    const int wr = (wave & 1) * 32, wc = (wave >> 1) * 32;

    f32x4 acc[2][2];
#pragma unroll
    for (int i = 0; i < 2; ++i)
#pragma unroll
        for (int j = 0; j < 2; ++j) acc[i][j] = (f32x4){0.f, 0.f, 0.f, 0.f};

    // per-lane global source: row = wave*16 + lane/4, col-seg = (lane&3)*16B
    const int grow = wave * 16 + (lane >> 2);
    const int gcol = (lane & 3) * 8;
    const ushort_t* Ag = A  + (size_t)(m0 + grow) * 512 + gcol;
    const ushort_t* Bg = BT + (size_t)(n0 + grow) * 512 + gcol;
    const int fr = lane & 15, fc = (lane >> 4) * 8;

    // prologue: stage kt=0 into buffer 0
#pragma unroll
    for (int t = 0; t < 2; ++t) {
        glds16(Ag + t * 32, &As[0][t][wave * 16][0]);
        glds16(Bg + t * 32, &Bs[0][t][wave * 16][0]);
    }
    __syncthreads();   // vmcnt(0) drained -> buffer 0 visible

    int p = 0;
    for (int kt = 0; kt < 8; ++kt) {
        // issue next-tile prefetch FIRST — latency hides under this kt's MFMA
        if (kt < 7) {
#pragma unroll
            for (int t = 0; t < 2; ++t) {
                glds16(Ag + (kt + 1) * 64 + t * 32, &As[p ^ 1][t][wave * 16][0]);
                glds16(Bg + (kt + 1) * 64 + t * 32, &Bs[p ^ 1][t][wave * 16][0]);
            }
        }
#pragma unroll
        for (int t = 0; t < 2; ++t) {
            bf16x8 af[2], bf[2];
#pragma unroll
            for (int i = 0; i < 2; ++i) af[i] = *(const bf16x8*)&As[p][t][wr + i * 16 + fr][fc];
#pragma unroll
            for (int j = 0; j < 2; ++j) bf[j] = *(const bf16x8*)&Bs[p][t][wc + j * 16 + fr][fc];
#pragma unroll
            for (int i = 0; i < 2; ++i)
#pragma unroll
                for (int j = 0; j < 2; ++j)
                    acc[i][j] = __builtin_amdgcn_mfma_f32_16x16x32_bf16(af[i], bf[j], acc[i][j], 0, 0, 0);
        }
        __syncthreads();   // drains prefetch (vmcnt 0) + guards buffer reuse
        p ^= 1;
    }

    const int col_l = lane & 15, row_l = (lane >> 4) * 4;

    if (MODE == 0 && n0 >= 1024) {
        // V part: LDS-transposed coalesced bf16 stores (R16)
        const int e0 = n0 - 1024;
#pragma unroll
        for (int j = 0; j < 2; ++j) {
            const float bvv = bias[n0 + wc + j * 16 + col_l];
#pragma unroll
            for (int i = 0; i < 2; ++i) {
                f32x4 v = acc[i][j];
#pragma unroll
                for (int r = 0; r < 4; ++r)
                    epV[wc + j * 16 + col_l][wr + i * 16 + row_l + r] = v[r] + bvv;
            }
        }
        __syncthreads();
        const int e = tid >> 2, ts = (tid & 3) * 16;
        const int bb = m0 >> 11, tok = (m0 & 2047) + ts;
        uint o[8];
#pragma unroll
        for (int k = 0; k < 8; ++k)
            o[k] = f2bf(epV[e][ts + 2 * k]) | (f2bf(epV[e][ts + 2 * k + 1]) << 16);
        ushort_t* dst = &oVT[((size_t)(bb * 512 + e0 + e)) * 2048 + tok];
        *(uint4*)dst       = *(const uint4*)&o[0];
        *(uint4*)(dst + 8) = *(const uint4*)&o[4];
        return;
    }

    // LDS-transposed coalesced epilogue (QK bf16 / out-proj fp32); ep overlays tiles
    const float scale = (MODE == 0 && n0 < 512) ? CEXP : 1.0f;
    float bv[2];
#pragma unroll
    for (int j = 0; j < 2; ++j) bv[j] = bias[n0 + wc + j * 16 + col_l];

    const int erow = tid >> 3, eseg = (tid & 7) * 8;
#pragma unroll
    for (int c = 0; c < 2; ++c) {
        __syncthreads();
        if (wr == c * 32) {
#pragma unroll
            for (int i = 0; i < 2; ++i) {
#pragma unroll
                for (int j = 0; j < 2; ++j) {
                    f32x4 v = acc[i][j];
#pragma unroll
                    for (int r = 0; r < 4; ++r)
                        ep[i * 16 + row_l + r][wc + j * 16 + col_l] = (v[r] + bv[j]) * scale;
                }
            }
        }
        __syncthreads();
        const int grow2 = m0 + c * 32 + erow;
        if (MODE == 0) {
            uint4 o0;
#pragma unroll
            for (int k = 0; k < 4; ++k) {
                ((uint*)&o0)[k] = f2bf(ep[erow][eseg + k * 2])
                                | (f2bf(ep[erow][eseg + k * 2 + 1]) << 16);
            }
            *(uint4*)&oQK[(size_t)grow2 * 1024 + n0 + eseg] = o0;
        } else {
#pragma unroll
            for (int k = 0; k < 2; ++k) {
                f32x4 v = *(const f32x4*)&ep[erow][eseg + k * 4];
                *(f32x4*)&oC[(size_t)grow2 * 512 + n0 + eseg + k * 4] = v;
            }
        }
    }
}

// ---------------------------------------------------------------------------
// R16: FUSED combine + out-projection.
// out[row=(b,tok)][col] = sum_e ((O0+O1)[b][e][tok] * invl[b][e>>6][tok]) * Wo[col][e] + bo
// Each K-tile (64 e) = exactly one head h = kt, so invl is a per-lane scalar
// (lane = tok). A-staging: coalesced ushort reads of Opart [e][tok], combine
// (O0+O1)*inv in fp32, f2bf — the EXACT per-element op combine2Tb performed —
// then ds_write_b128 into Ls[tok][e]. Fragments/MFMA/epilogue identical to the
// old gemm64<1>, so the output is bit-identical to combine2Tb + gemm64<1>.
// T14 reg-prefetch: next kt's 16 ushort pairs + Lp loads issue under MFMAs.
// ---------------------------------------------------------------------------
__global__ __launch_bounds__(256)
void gemmOut(const ushort_t* __restrict__ Op, const float* __restrict__ Lp,
             const ushort_t* __restrict__ W, const float* __restrict__ bias,
             float* __restrict__ oC) {
    __shared__ __align__(16) char smem[16896];
    ushort_t (*Ls)[68]     = (ushort_t (*)[68])smem;                  // [tok][e] 8704 B
    ushort_t (*Bs)[64][32] = (ushort_t (*)[64][32])(smem + 8704);     // [t][n][k] 8192 B
    float (*ep)[68]        = (float (*)[68])smem;                     // epilogue overlay

    const int tid = threadIdx.x, wave = tid >> 6, lane = tid & 63;
    const int m0 = blockIdx.x * 64, n0 = blockIdx.y * 64;
    const int wr = (wave & 1) * 32, wc = (wave >> 1) * 32;

    f32x4 acc[2][2];
#pragma unroll
    for (int i = 0; i < 2; ++i)
#pragma unroll
        for (int j = 0; j < 2; ++j) acc[i][j] = (f32x4){0.f, 0.f, 0.f, 0.f};

    const int bb = m0 >> 11;
    const int tok = (m0 & 2047) + lane;           // this lane's token (staging)
    const ushort_t* OpA = Op + ((size_t)(bb * 512)) * 2048 + tok;   // + e*2048
    const ushort_t* OpB = OpA + 4194304;                            // slice 1
    const float*    LpA = Lp + (size_t)bb * 16384 + (m0 & 2047) + lane;

    const int grow = wave * 16 + (lane >> 2);
    const int gcol = (lane & 3) * 8;
    const ushort_t* Bg = W + (size_t)(n0 + grow) * 512 + gcol;
    const int fr = lane & 15, fc = (lane >> 4) * 8;

    // prologue: raw loads for kt=0
    uint u0[16], u1[16];
    float l0 = LpA[0], l1 = LpA[65536];
#pragma unroll
    for (int eo = 0; eo < 16; ++eo) {
        const size_t off = (size_t)(wave * 16 + eo) * 2048;
        u0[eo] = OpA[off];  u1[eo] = OpB[off];
    }

    for (int kt = 0; kt < 8; ++kt) {
        // combine + scale + pack (fp32 math identical to combine2Tb)
        const float inv = 1.0f / (l0 + l1);
        uint pk[8];
#pragma unroll
        for (int k = 0; k < 8; ++k) {
            const float sa = __builtin_bit_cast(float, u0[2 * k] << 16)
                           + __builtin_bit_cast(float, u1[2 * k] << 16);
            const float sb = __builtin_bit_cast(float, u0[2 * k + 1] << 16)
                           + __builtin_bit_cast(float, u1[2 * k + 1] << 16);
            pk[k] = f2bf(sa * inv) | (f2bf(sb * inv) << 16);
        }
        __syncthreads();   // prior-iteration fragment reads done
        *(uint4*)&Ls[lane][wave * 16]     = *(const uint4*)&pk[0];
        *(uint4*)&Ls[lane][wave * 16 + 8] = *(const uint4*)&pk[4];
#pragma unroll
        for (int t = 0; t < 2; ++t)
            glds16(Bg + kt * 64 + t * 32, &Bs[t][wave * 16][0]);
        __syncthreads();   // A writes + B glds16 (vmcnt 0) visible

        // T14: issue next kt's raw loads before the MFMAs
        if (kt < 7) {
            l0 = LpA[(kt + 1) * 2048];  l1 = LpA[65536 + (kt + 1) * 2048];
#pragma unroll
            for (int eo = 0; eo < 16; ++eo) {
                const size_t off = (size_t)((kt + 1) * 64 + wave * 16 + eo) * 2048;
                u0[eo] = OpA[off];  u1[eo] = OpB[off];
            }
        }
#pragma unroll
        for (int t = 0; t < 2; ++t) {
            bf16x8 af[2], bf[2];
#pragma unroll
            for (int i = 0; i < 2; ++i) af[i] = *(const bf16x8*)&Ls[wr + i * 16 + fr][t * 32 + fc];
#pragma unroll
            for (int j = 0; j < 2; ++j) bf[j] = *(const bf16x8*)&Bs[t][wc + j * 16 + fr][fc];
#pragma unroll
            for (int i = 0; i < 2; ++i)
#pragma unroll
                for (int j = 0; j < 2; ++j)
                    acc[i][j] = __builtin_amdgcn_mfma_f32_16x16x32_bf16(af[i], bf[j], acc[i][j], 0, 0, 0);
        }
    }

    // epilogue: LDS-transposed coalesced fp32 stores + bias (same as old MODE 1)
    const int col_l = lane & 15, row_l = (lane >> 4) * 4;
    float bv[2];
#pragma unroll
    for (int j = 0; j < 2; ++j) bv[j] = bias[n0 + wc + j * 16 + col_l];

    const int erow = tid >> 3, eseg = (tid & 7) * 8;
#pragma unroll
    for (int c = 0; c < 2; ++c) {
        __syncthreads();
        if (wr == c * 32) {
#pragma unroll
            for (int i = 0; i < 2; ++i)
#pragma unroll
                for (int j = 0; j < 2; ++j) {
                    f32x4 v = acc[i][j];
#pragma unroll
                    for (int r = 0; r < 4; ++r)
                        ep[i * 16 + row_l + r][wc + j * 16 + col_l] = v[r] + bv[j];
                }
        }
        __syncthreads();
        const int grow2 = m0 + c * 32 + erow;
#pragma unroll
        for (int k = 0; k < 2; ++k) {
            f32x4 v = *(const f32x4*)&ep[erow][eseg + k * 4];
            *(f32x4*)&oC[(size_t)grow2 * 512 + n0 + eseg + k * 4] = v;
        }
    }
}

// ---------------------------------------------------------------------------
// MFMA flash attention, O^T formulation; 64 q-rows per wave. R9-passing
// version VERBATIM (dbuf K/V, permlane32_swap, setprio, v_perm exp-pack,
// ones-MFMA accL). ~204 unified regs -> 2 waves/SIMD hard cap.
// ---------------------------------------------------------------------------
template<int NSLICE>
__global__ __launch_bounds__(256, 2)
void attn_mfma(const ushort_t* __restrict__ QK, const ushort_t* __restrict__ VT,
               ushort_t* __restrict__ Op, float* __restrict__ Lp,
               ushort_t* __restrict__ AO) {
    __shared__ ushort_t Ks[2][64][72];    // [buf][krow][d]
    __shared__ ushort_t Vs[2][64][72];    // [buf][d][krow]  (V^T tile)

    const int tid = threadIdx.x, w = tid >> 6, lane = tid & 63;
    const int qt = blockIdx.x, bh = blockIdx.y, b = bh >> 3, h = bh & 7;
    const int slice = (NSLICE > 1) ? blockIdx.z : 0;
    const int l31 = lane & 31, lhi = lane >> 5;

    const int tok0 = qt * 256 + w * 64 + l31;   // q-group g adds g*32
    bf16x8 qf[2][4];
#pragma unroll
    for (int g = 0; g < 2; ++g)
#pragma unroll
        for (int ks = 0; ks < 4; ++ks)
            qf[g][ks] = *(const bf16x8*)&QK[(size_t)(b * NSEQ + tok0 + g * 32) * 1024
                                            + h * 64 + ks * 16 + lhi * 8];

    f32x16 accO[2][2];   // [g][d-half]
    f32x16 accL[2];      // [g] row-sum accumulator (ones-MFMA)
#pragma unroll
    for (int g = 0; g < 2; ++g) {
#pragma unroll
        for (int i = 0; i < 16; ++i) { accO[g][0][i] = 0.f; accO[g][1][i] = 0.f; accL[g][i] = 0.f; }
    }
    union { uint u[4]; bf16x8 v; } ONE;
    ONE.u[0] = 0x3f803f80u; ONE.u[1] = 0x3f803f80u;
    ONE.u[2] = 0x3f803f80u; ONE.u[3] = 0x3f803f80u;

    const int sr = tid & 63, sc = (tid >> 6) * 16;
    const ushort_t* Kg = QK + (size_t)(b * NSEQ) * 1024 + 512 + h * 64;
    const ushort_t* Vg = VT + ((size_t)(b * 512 + h * 64)) * 2048;

    const int kt0 = slice * (32 / NSLICE), kt1 = kt0 + 32 / NSLICE;

    // prologue: stage tile kt0 into buffer 0
    {
        const int k0 = kt0 * 64;
        uint4 kv0 = *(const uint4*)&Kg[(size_t)(k0 + sr) * 1024 + sc];
        uint4 kv1 = *(const uint4*)&Kg[(size_t)(k0 + sr) * 1024 + sc + 8];
        uint4 vv0 = *(const uint4*)&Vg[(size_t)sr * 2048 + k0 + sc];
        uint4 vv1 = *(const uint4*)&Vg[(size_t)sr * 2048 + k0 + sc + 8];
        *(uint4*)&Ks[0][sr][sc] = kv0;  *(uint4*)&Ks[0][sr][sc + 8] = kv1;
        *(uint4*)&Vs[0][sr][sc] = vv0;  *(uint4*)&Vs[0][sr][sc + 8] = vv1;
        __syncthreads();
    }

    const uint psel = 0x07060302u;   // v_perm selector: {ua.b2,ua.b3,ub.b2,ub.b3}
    int p = 0;
#pragma unroll 2
    for (int kt = kt0; kt < kt1; ++kt) {
        // issue next-tile global loads FIRST — latency hides under compute
        uint4 kv0, kv1, vv0, vv1;
        const bool pf = (kt + 1 < kt1);
        if (pf) {
            const int k0 = (kt + 1) * 64;
            kv0 = *(const uint4*)&Kg[(size_t)(k0 + sr) * 1024 + sc];
            kv1 = *(const uint4*)&Kg[(size_t)(k0 + sr) * 1024 + sc + 8];
            vv0 = *(const uint4*)&Vg[(size_t)sr * 2048 + k0 + sc];
            vv1 = *(const uint4*)&Vg[(size_t)sr * 2048 + k0 + sc + 8];
        }

        // compute from buffer p
#pragma unroll
        for (int ms = 0; ms < 2; ++ms) {   // krow halves 0..31 / 32..63
            bf16x8 ka[4];
#pragma unroll
            for (int ks = 0; ks < 4; ++ks)
                ka[ks] = *(const bf16x8*)&Ks[p][ms * 32 + l31][ks * 16 + lhi * 8];

            f32x16 st[2];
#pragma unroll
            for (int g = 0; g < 2; ++g)
#pragma unroll
                for (int i = 0; i < 16; ++i) st[g][i] = 0.f;
            __builtin_amdgcn_s_setprio(1);
#pragma unroll
            for (int ks = 0; ks < 4; ++ks) {
                st[0] = __builtin_amdgcn_mfma_f32_32x32x16_bf16(ka[ks], qf[0][ks], st[0], 0, 0, 0);
                st[1] = __builtin_amdgcn_mfma_f32_32x32x16_bf16(ka[ks], qf[1][ks], st[1], 0, 0, 0);
            }
            __builtin_amdgcn_s_setprio(0);

            uint dd[2][8];
#pragma unroll
            for (int g = 0; g < 2; ++g)
#pragma unroll
                for (int i = 0; i < 8; ++i) {
                    uint ua = __builtin_bit_cast(uint, __builtin_amdgcn_exp2f(st[g][2 * i]));
                    uint ub = __builtin_bit_cast(uint, __builtin_amdgcn_exp2f(st[g][2 * i + 1]));
                    uint r;
                    // r = (ua>>16) | (ub & 0xffff0000) — truncated bf16 pair
                    asm("v_perm_b32 %0, %1, %2, %3" : "=v"(r) : "v"(ub), "v"(ua), "v"(psel));
                    dd[g][i] = r;
                }

#pragma unroll
            for (int s = 0; s < 2; ++s) {
                const int step = ms * 2 + s;
                bf16x8 va0 = *(const bf16x8*)&Vs[p][l31][step * 16 + lhi * 8];
                bf16x8 va1 = *(const bf16x8*)&Vs[p][32 + l31][step * 16 + lhi * 8];
#pragma unroll
                for (int g = 0; g < 2; ++g) {
                    // == v_permlane32_swap_b32 semantics (Dst.row1 <-> Src.row0)
                    uint a0 = dd[g][4 * s + 0], a2 = dd[g][4 * s + 2];
                    uint a1 = dd[g][4 * s + 1], a3 = dd[g][4 * s + 3];
                    asm("v_permlane32_swap_b32 %0, %1" : "+v"(a0), "+v"(a2));
                    asm("v_permlane32_swap_b32 %0, %1" : "+v"(a1), "+v"(a3));
                    union { uint u[4]; bf16x8 v; } B;
                    B.u[0] = a0; B.u[1] = a1; B.u[2] = a2; B.u[3] = a3;
                    __builtin_amdgcn_s_setprio(1);
                    accO[g][0] = __builtin_amdgcn_mfma_f32_32x32x16_bf16(va0, B.v, accO[g][0], 0, 0, 0);
                    accO[g][1] = __builtin_amdgcn_mfma_f32_32x32x16_bf16(va1, B.v, accO[g][1], 0, 0, 0);
                    accL[g]    = __builtin_amdgcn_mfma_f32_32x32x16_bf16(ONE.v, B.v, accL[g], 0, 0, 0);
                    __builtin_amdgcn_s_setprio(0);
                }
            }
        }

        // write prefetched tile into the other buffer; one barrier per kt.
        if (pf) {
            *(uint4*)&Ks[p ^ 1][sr][sc] = kv0;  *(uint4*)&Ks[p ^ 1][sr][sc + 8] = kv1;
            *(uint4*)&Vs[p ^ 1][sr][sc] = vv0;  *(uint4*)&Vs[p ^ 1][sr][sc + 8] = vv1;
        }
        __syncthreads();
        p ^= 1;
    }

    // accL[g][r] == l[qrow] for every r — no reduction needed.
    if (NSLICE == 1) {
#pragma unroll
        for (int g = 0; g < 2; ++g) {
            const float inv = 1.0f / accL[g][0];
#pragma unroll
            for (int hf = 0; hf < 2; ++hf)
#pragma unroll
                for (int r = 0; r < 16; ++r) {
                    const int d = (r & 3) + 8 * (r >> 2) + 4 * lhi + 32 * hf;
                    AO[((size_t)(b * NSEQ + tok0 + g * 32)) * 512 + h * 64 + d] =
                        (ushort_t)f2bf(accO[g][hf][r] * inv);
                }
        }
    } else {
        if (lane < 32) {
#pragma unroll
            for (int g = 0; g < 2; ++g)
                Lp[(size_t)slice * 65536 + bh * 2048 + tok0 + g * 32] = accL[g][0];
        }
        ushort_t* Os = Op + (size_t)slice * 4194304;
#pragma unroll
        for (int g = 0; g < 2; ++g)
#pragma unroll
            for (int hf = 0; hf < 2; ++hf)
#pragma unroll
                for (int r = 0; r < 16; ++r) {
                    const int d = (r & 3) + 8 * (r >> 2) + 4 * lhi + 32 * hf;
                    Os[((size_t)(bh * 64 + d)) * 2048 + tok0 + g * 32] =
                        (ushort_t)f2bf(accO[g][hf][r]);
                }
    }
}

// ---------------------------------------------------------------------------
// Combine 2 split-K bf16 partials (FALLBACK ONLY, !split path unused in
// practice): AO[tok][e] = sum_s O_s / sum_s l_s.
// ---------------------------------------------------------------------------
__global__ __launch_bounds__(256)
void combine2Tb(const ushort_t* __restrict__ Op, const float* __restrict__ Lp,
                ushort_t* __restrict__ AO) {
    __shared__ float T[64][68];
    const int tid = threadIdx.x;
    const int tc = blockIdx.x, bh = blockIdx.y;
    const int b = bh >> 3, h = bh & 7;
    const int tok0 = tc * 64;

    const int d = tid >> 2, ts = (tid & 3) * 16;
    float acc[16];
#pragma unroll
    for (int i = 0; i < 16; ++i) acc[i] = 0.f;
#pragma unroll
    for (int s = 0; s < 2; ++s) {
        const ushort_t* P = Op + (size_t)s * 4194304
                               + ((size_t)(bh * 64 + d)) * 2048 + tok0 + ts;
#pragma unroll
        for (int k2 = 0; k2 < 2; ++k2) {
            uint4 u = *(const uint4*)(P + 8 * k2);
#pragma unroll
            for (int j = 0; j < 4; ++j) {
                uint uw = ((const uint*)&u)[j];
                acc[k2 * 8 + 2 * j]     += __builtin_bit_cast(float, uw << 16);
                acc[k2 * 8 + 2 * j + 1] += __builtin_bit_cast(float, uw & 0xffff0000u);
            }
        }
    }
#pragma unroll
    for (int k = 0; k < 4; ++k)
        *(f32x4*)&T[d][ts + 4 * k] = *(const f32x4*)&acc[4 * k];
    __syncthreads();

    const int tk = tid >> 2, ds = (tid & 3) * 16;
    const int tok = tok0 + tk;
    const float inv = 1.0f / (Lp[bh * 2048 + tok] + Lp[65536 + bh * 2048 + tok]);
    uint o[8];
#pragma unroll
    for (int k = 0; k < 8; ++k) {
        float a = T[ds + 2 * k][tk] * inv;
        float c = T[ds + 2 * k + 1][tk] * inv;
        o[k] = f2bf(a) | (f2bf(c) << 16);
    }
    ushort_t* dst = AO + ((size_t)(b * NSEQ + tok)) * 512 + h * 64 + ds;
    *(uint4*)dst       = *(const uint4*)&o[0];
    *(uint4*)(dst + 8) = *(const uint4*)&o[4];
}

// ---------------------------------------------------------------------------
extern "C" void kernel_launch(void* const* d_in, const int* in_sizes, int n_in,
                              void* d_out, int out_size, void* d_ws, size_t ws_size,
                              hipStream_t stream) {
    const float* x  = (const float*)d_in[0];
    const float* Wq = (const float*)d_in[1];
    const float* bq = (const float*)d_in[2];
    const float* Wk = (const float*)d_in[3];
    const float* bk = (const float*)d_in[4];
    const float* Wv = (const float*)d_in[5];
    const float* bv = (const float*)d_in[6];
    const float* Wo = (const float*)d_in[7];
    const float* bo = (const float*)d_in[8];

    char* ws = (char*)d_ws;
    ushort_t* xb    = (ushort_t*)(ws);                       //  8,388,608 B
    ushort_t* Wqkvb = (ushort_t*)(ws + 8388608);             //  1,572,864 B
    ushort_t* Wob   = (ushort_t*)(ws + 9961472);             //    524,288 B
    float*    bqkv  = (float*)   (ws + 10485760);            //      6,144 B
    ushort_t* QKb   = (ushort_t*)(ws + 10491904);            // 16,777,216 B
    ushort_t* VTg   = (ushort_t*)(ws + 27269120);            //  8,388,608 B
    ushort_t* AOb   = (ushort_t*)(ws + 35657728);            //  8,388,608 B (fallback only)
    ushort_t* Opart = (ushort_t*)(ws + 44046336);            // 16,777,216 B (2 slices bf16)
    float*    Lpart = (float*)   (ws);                       //    524,288 B overlay on xb
                                                             //  (xb dead after gemm<0>)
    const bool split = ws_size >= 78125056;

    prep<<<4096, 256, 0, stream>>>(x, Wq, Wk, Wv, Wo, bq, bk, bv,
                                   xb, Wqkvb, bqkv, Wob);
    gemm64<0><<<dim3(128, 24), 256, 0, stream>>>(xb, Wqkvb, bqkv, QKb, VTg, nullptr);
    if (split) {
        attn_mfma<2><<<dim3(8, 32, 2), 256, 0, stream>>>(QKb, VTg, Opart, Lpart, nullptr);
        gemmOut<<<dim3(128, 8), 256, 0, stream>>>(Opart, Lpart, Wob, bo, (float*)d_out);
    } else {
        attn_mfma<1><<<dim3(8, 32, 1), 256, 0, stream>>>(QKb, VTg, nullptr, nullptr, AOb);
        gemm64<1><<<dim3(128, 8), 256, 0, stream>>>(AOb, Wob, bo, nullptr, nullptr, (float*)d_out);
    }
}

// Round 10
// 167.470 us; speedup vs baseline: 1.0653x; 1.0653x over previous
//
#include <hip/hip_runtime.h>

typedef float f32x4 __attribute__((ext_vector_type(4)));
typedef float f32x16 __attribute__((ext_vector_type(16)));
typedef short bf16x8 __attribute__((ext_vector_type(8)));
typedef unsigned int uint;
typedef unsigned short ushort_t;

#define EMB    512
#define NSEQ   2048
#define NBATCH 4
#define NHEAD  8
#define MROWS  (NBATCH * NSEQ)   // 8192
#define CEXP   0.06375872f       // log2(e) / sqrt(512)

// round-to-nearest-even fp32 -> bf16 (bit trick)
__device__ __forceinline__ uint f2bf(float x) {
    uint u = __builtin_bit_cast(uint, x);
    return (u + 0x7fffu + ((u >> 16) & 1u)) >> 16;
}

// async global->LDS, 16B per lane; LDS dest = wave-uniform base + lane*16
__device__ __forceinline__ void glds16(const void* g, void* l) {
    __builtin_amdgcn_global_load_lds(
        (const __attribute__((address_space(1))) uint*)g,
        (__attribute__((address_space(3))) uint*)l, 16, 0, 0);
}

// ---------------------------------------------------------------------------
// Prep: x -> bf16; Wq|Wk|Wv -> Wqkvb bf16 [1536][512]; biases concat; Wo -> bf16
// ---------------------------------------------------------------------------
__global__ __launch_bounds__(256)
void prep(const float* __restrict__ x,
          const float* __restrict__ Wq, const float* __restrict__ Wk,
          const float* __restrict__ Wv, const float* __restrict__ Wo,
          const float* __restrict__ bq, const float* __restrict__ bk,
          const float* __restrict__ bv,
          ushort_t* __restrict__ xb, ushort_t* __restrict__ Wqkvb,
          float* __restrict__ bqkv, ushort_t* __restrict__ Wob) {
    int t = blockIdx.x * 256 + threadIdx.x;   // f4-group index, 1048576 total
    {
        float4 v = ((const float4*)x)[t];
        uint2 p;
        p.x = f2bf(v.x) | (f2bf(v.y) << 16);
        p.y = f2bf(v.z) | (f2bf(v.w) << 16);
        ((uint2*)xb)[t] = p;
    }
    if (t < 65536) {   // 512*512/4 groups per weight
        float4 a = ((const float4*)Wq)[t];
        float4 b = ((const float4*)Wk)[t];
        float4 c = ((const float4*)Wv)[t];
        float4 d = ((const float4*)Wo)[t];
        uint2 p;
        p.x = f2bf(a.x) | (f2bf(a.y) << 16); p.y = f2bf(a.z) | (f2bf(a.w) << 16);
        ((uint2*)Wqkvb)[t] = p;
        p.x = f2bf(b.x) | (f2bf(b.y) << 16); p.y = f2bf(b.z) | (f2bf(b.w) << 16);
        ((uint2*)Wqkvb)[t + 65536] = p;
        p.x = f2bf(c.x) | (f2bf(c.y) << 16); p.y = f2bf(c.z) | (f2bf(c.w) << 16);
        ((uint2*)Wqkvb)[t + 131072] = p;
        p.x = f2bf(d.x) | (f2bf(d.y) << 16); p.y = f2bf(d.z) | (f2bf(d.w) << 16);
        ((uint2*)Wob)[t] = p;
    }
    if (t < 512) {
        bqkv[t] = bq[t]; bqkv[512 + t] = bk[t]; bqkv[1024 + t] = bv[t];
    }
}

// ---------------------------------------------------------------------------
// GEMM C[8192 x N] = A[8192x512]bf16 * BT[Nx512]bf16 + bias, 64x64 tile,
// R15 2-phase double-buffered K-loop. R16's V-epilogue kept: LDS transpose ->
// 128B coalesced runs (was 8B scattered at 4KB stride). Values bit-identical.
// MODE 0: QKV (N=1536); MODE 1: out proj (N=512), fp32 + bias.
// ---------------------------------------------------------------------------
template<int MODE>
__global__ __launch_bounds__(256)
void gemm64(const ushort_t* __restrict__ A, const ushort_t* __restrict__ BT,
            const float* __restrict__ bias, ushort_t* __restrict__ oQK,
            ushort_t* __restrict__ oVT, float* __restrict__ oC) {
    __shared__ __align__(16) char smem[32768];
    ushort_t (*As)[2][64][32] = (ushort_t (*)[2][64][32])smem;           // 16KB
    ushort_t (*Bs)[2][64][32] = (ushort_t (*)[2][64][32])(smem + 16384); // 16KB
    float (*ep)[68] = (float (*)[68])smem;    // Q/K + MODE1 epilogue overlay
    float (*epV)[69] = (float (*)[69])smem;   // V epilogue overlay (64x69 fp32)

    const int tid = threadIdx.x, wave = tid >> 6, lane = tid & 63;
    const int m0 = blockIdx.x * 64, n0 = blockIdx.y * 64;
    const int wr = (wave & 1) * 32, wc = (wave >> 1) * 32;

    f32x4 acc[2][2];
#pragma unroll
    for (int i = 0; i < 2; ++i)
#pragma unroll
        for (int j = 0; j < 2; ++j) acc[i][j] = (f32x4){0.f, 0.f, 0.f, 0.f};

    // per-lane global source: row = wave*16 + lane/4, col-seg = (lane&3)*16B
    const int grow = wave * 16 + (lane >> 2);
    const int gcol = (lane & 3) * 8;
    const ushort_t* Ag = A  + (size_t)(m0 + grow) * 512 + gcol;
    const ushort_t* Bg = BT + (size_t)(n0 + grow) * 512 + gcol;
    const int fr = lane & 15, fc = (lane >> 4) * 8;

    // prologue: stage kt=0 into buffer 0
#pragma unroll
    for (int t = 0; t < 2; ++t) {
        glds16(Ag + t * 32, &As[0][t][wave * 16][0]);
        glds16(Bg + t * 32, &Bs[0][t][wave * 16][0]);
    }
    __syncthreads();   // vmcnt(0) drained -> buffer 0 visible

    int p = 0;
    for (int kt = 0; kt < 8; ++kt) {
        // issue next-tile prefetch FIRST — latency hides under this kt's MFMA
        if (kt < 7) {
#pragma unroll
            for (int t = 0; t < 2; ++t) {
                glds16(Ag + (kt + 1) * 64 + t * 32, &As[p ^ 1][t][wave * 16][0]);
                glds16(Bg + (kt + 1) * 64 + t * 32, &Bs[p ^ 1][t][wave * 16][0]);
            }
        }
#pragma unroll
        for (int t = 0; t < 2; ++t) {
            bf16x8 af[2], bf[2];
#pragma unroll
            for (int i = 0; i < 2; ++i) af[i] = *(const bf16x8*)&As[p][t][wr + i * 16 + fr][fc];
#pragma unroll
            for (int j = 0; j < 2; ++j) bf[j] = *(const bf16x8*)&Bs[p][t][wc + j * 16 + fr][fc];
#pragma unroll
            for (int i = 0; i < 2; ++i)
#pragma unroll
                for (int j = 0; j < 2; ++j)
                    acc[i][j] = __builtin_amdgcn_mfma_f32_16x16x32_bf16(af[i], bf[j], acc[i][j], 0, 0, 0);
        }
        __syncthreads();   // drains prefetch (vmcnt 0) + guards buffer reuse
        p ^= 1;
    }

    const int col_l = lane & 15, row_l = (lane >> 4) * 4;

    if (MODE == 0 && n0 >= 1024) {
        // V part: LDS-transposed coalesced bf16 stores
        const int e0 = n0 - 1024;
#pragma unroll
        for (int j = 0; j < 2; ++j) {
            const float bvv = bias[n0 + wc + j * 16 + col_l];
#pragma unroll
            for (int i = 0; i < 2; ++i) {
                f32x4 v = acc[i][j];
#pragma unroll
                for (int r = 0; r < 4; ++r)
                    epV[wc + j * 16 + col_l][wr + i * 16 + row_l + r] = v[r] + bvv;
            }
        }
        __syncthreads();
        const int e = tid >> 2, ts = (tid & 3) * 16;
        const int bb = m0 >> 11, tok = (m0 & 2047) + ts;
        uint o[8];
#pragma unroll
        for (int k = 0; k < 8; ++k)
            o[k] = f2bf(epV[e][ts + 2 * k]) | (f2bf(epV[e][ts + 2 * k + 1]) << 16);
        ushort_t* dst = &oVT[((size_t)(bb * 512 + e0 + e)) * 2048 + tok];
        *(uint4*)dst       = *(const uint4*)&o[0];
        *(uint4*)(dst + 8) = *(const uint4*)&o[4];
        return;
    }

    // LDS-transposed coalesced epilogue (QK bf16 / out-proj fp32); ep overlays tiles
    const float scale = (MODE == 0 && n0 < 512) ? CEXP : 1.0f;
    float bv[2];
#pragma unroll
    for (int j = 0; j < 2; ++j) bv[j] = bias[n0 + wc + j * 16 + col_l];

    const int erow = tid >> 3, eseg = (tid & 7) * 8;
#pragma unroll
    for (int c = 0; c < 2; ++c) {
        __syncthreads();
        if (wr == c * 32) {
#pragma unroll
            for (int i = 0; i < 2; ++i) {
#pragma unroll
                for (int j = 0; j < 2; ++j) {
                    f32x4 v = acc[i][j];
#pragma unroll
                    for (int r = 0; r < 4; ++r)
                        ep[i * 16 + row_l + r][wc + j * 16 + col_l] = (v[r] + bv[j]) * scale;
                }
            }
        }
        __syncthreads();
        const int grow2 = m0 + c * 32 + erow;
        if (MODE == 0) {
            uint4 o0;
#pragma unroll
            for (int k = 0; k < 4; ++k) {
                ((uint*)&o0)[k] = f2bf(ep[erow][eseg + k * 2])
                                | (f2bf(ep[erow][eseg + k * 2 + 1]) << 16);
            }
            *(uint4*)&oQK[(size_t)grow2 * 1024 + n0 + eseg] = o0;
        } else {
#pragma unroll
            for (int k = 0; k < 2; ++k) {
                f32x4 v = *(const f32x4*)&ep[erow][eseg + k * 4];
                *(f32x4*)&oC[(size_t)grow2 * 512 + n0 + eseg + k * 4] = v;
            }
        }
    }
}

// ---------------------------------------------------------------------------
// MFMA flash attention, O^T formulation; 64 q-rows per wave.
// R17: KVBLK=128 — each kt now processes a 128-wide K/V tile (4 ms quarters),
//      HALVING barrier events (32 -> 16) and their lgkm/vm drains, which at
//      the 2-waves/SIMD residency cap (204 unified regs) are the dominant
//      exposed serial cost (~3700 cyc/kt wall vs ~700 cyc issue work).
//      The sequence of 32-k-chunk operations (MFMA order, exp2, packing,
//      accO/accL accumulation order over k=0..2047) is UNCHANGED ->
//      bit-identical output to R9/R15. LDS 71.7 KB (2 blocks/CU, reg-capped
//      anyway). Staging regs +16 -> ~220 unified, still 2 waves/SIMD.
// ---------------------------------------------------------------------------
template<int NSLICE>
__global__ __launch_bounds__(256, 2)
void attn_mfma(const ushort_t* __restrict__ QK, const ushort_t* __restrict__ VT,
               ushort_t* __restrict__ Op, float* __restrict__ Lp,
               ushort_t* __restrict__ AO) {
    __shared__ ushort_t Ks[2][128][72];   // [buf][krow][d]
    __shared__ ushort_t Vs[2][64][136];   // [buf][d][krow]  (V^T tile)

    const int tid = threadIdx.x, w = tid >> 6, lane = tid & 63;
    const int qt = blockIdx.x, bh = blockIdx.y, b = bh >> 3, h = bh & 7;
    const int slice = (NSLICE > 1) ? blockIdx.z : 0;
    const int l31 = lane & 31, lhi = lane >> 5;

    const int tok0 = qt * 256 + w * 64 + l31;   // q-group g adds g*32
    bf16x8 qf[2][4];
#pragma unroll
    for (int g = 0; g < 2; ++g)
#pragma unroll
        for (int ks = 0; ks < 4; ++ks)
            qf[g][ks] = *(const bf16x8*)&QK[(size_t)(b * NSEQ + tok0 + g * 32) * 1024
                                            + h * 64 + ks * 16 + lhi * 8];

    f32x16 accO[2][2];   // [g][d-half]
    f32x16 accL[2];      // [g] row-sum accumulator (ones-MFMA)
#pragma unroll
    for (int g = 0; g < 2; ++g) {
#pragma unroll
        for (int i = 0; i < 16; ++i) { accO[g][0][i] = 0.f; accO[g][1][i] = 0.f; accL[g][i] = 0.f; }
    }
    union { uint u[4]; bf16x8 v; } ONE;
    ONE.u[0] = 0x3f803f80u; ONE.u[1] = 0x3f803f80u;
    ONE.u[2] = 0x3f803f80u; ONE.u[3] = 0x3f803f80u;

    const int sr = tid & 63, sc = (tid >> 6) * 16;
    const ushort_t* Kg = QK + (size_t)(b * NSEQ) * 1024 + 512 + h * 64;
    const ushort_t* Vg = VT + ((size_t)(b * 512 + h * 64)) * 2048;

    // 16 k-tiles of 128 total
    const int kt0 = slice * (16 / NSLICE), kt1 = kt0 + 16 / NSLICE;

    // prologue: stage tile kt0 into buffer 0
    {
        const int k0 = kt0 * 128;
        uint4 kv0 = *(const uint4*)&Kg[(size_t)(k0 + sr) * 1024 + sc];
        uint4 kv1 = *(const uint4*)&Kg[(size_t)(k0 + sr) * 1024 + sc + 8];
        uint4 kv2 = *(const uint4*)&Kg[(size_t)(k0 + 64 + sr) * 1024 + sc];
        uint4 kv3 = *(const uint4*)&Kg[(size_t)(k0 + 64 + sr) * 1024 + sc + 8];
        uint4 vv0 = *(const uint4*)&Vg[(size_t)sr * 2048 + k0 + sc];
        uint4 vv1 = *(const uint4*)&Vg[(size_t)sr * 2048 + k0 + sc + 8];
        uint4 vv2 = *(const uint4*)&Vg[(size_t)sr * 2048 + k0 + 64 + sc];
        uint4 vv3 = *(const uint4*)&Vg[(size_t)sr * 2048 + k0 + 64 + sc + 8];
        *(uint4*)&Ks[0][sr][sc] = kv0;       *(uint4*)&Ks[0][sr][sc + 8] = kv1;
        *(uint4*)&Ks[0][64 + sr][sc] = kv2;  *(uint4*)&Ks[0][64 + sr][sc + 8] = kv3;
        *(uint4*)&Vs[0][sr][sc] = vv0;       *(uint4*)&Vs[0][sr][sc + 8] = vv1;
        *(uint4*)&Vs[0][sr][64 + sc] = vv2;  *(uint4*)&Vs[0][sr][64 + sc + 8] = vv3;
        __syncthreads();
    }

    const uint psel = 0x07060302u;   // v_perm selector: {ua.b2,ua.b3,ub.b2,ub.b3}
    int p = 0;
#pragma unroll 2
    for (int kt = kt0; kt < kt1; ++kt) {
        // issue next-tile global loads FIRST — latency hides under compute
        uint4 kv0, kv1, kv2, kv3, vv0, vv1, vv2, vv3;
        const bool pf = (kt + 1 < kt1);
        if (pf) {
            const int k0 = (kt + 1) * 128;
            kv0 = *(const uint4*)&Kg[(size_t)(k0 + sr) * 1024 + sc];
            kv1 = *(const uint4*)&Kg[(size_t)(k0 + sr) * 1024 + sc + 8];
            kv2 = *(const uint4*)&Kg[(size_t)(k0 + 64 + sr) * 1024 + sc];
            kv3 = *(const uint4*)&Kg[(size_t)(k0 + 64 + sr) * 1024 + sc + 8];
            vv0 = *(const uint4*)&Vg[(size_t)sr * 2048 + k0 + sc];
            vv1 = *(const uint4*)&Vg[(size_t)sr * 2048 + k0 + sc + 8];
            vv2 = *(const uint4*)&Vg[(size_t)sr * 2048 + k0 + 64 + sc];
            vv3 = *(const uint4*)&Vg[(size_t)sr * 2048 + k0 + 64 + sc + 8];
        }

        // compute from buffer p: 4 quarters of 32 k-rows
#pragma unroll
        for (int ms = 0; ms < 4; ++ms) {
            bf16x8 ka[4];
#pragma unroll
            for (int ks = 0; ks < 4; ++ks)
                ka[ks] = *(const bf16x8*)&Ks[p][ms * 32 + l31][ks * 16 + lhi * 8];

            f32x16 st[2];
#pragma unroll
            for (int g = 0; g < 2; ++g)
#pragma unroll
                for (int i = 0; i < 16; ++i) st[g][i] = 0.f;
            __builtin_amdgcn_s_setprio(1);
#pragma unroll
            for (int ks = 0; ks < 4; ++ks) {
                st[0] = __builtin_amdgcn_mfma_f32_32x32x16_bf16(ka[ks], qf[0][ks], st[0], 0, 0, 0);
                st[1] = __builtin_amdgcn_mfma_f32_32x32x16_bf16(ka[ks], qf[1][ks], st[1], 0, 0, 0);
            }
            __builtin_amdgcn_s_setprio(0);

            uint dd[2][8];
#pragma unroll
            for (int g = 0; g < 2; ++g)
#pragma unroll
                for (int i = 0; i < 8; ++i) {
                    uint ua = __builtin_bit_cast(uint, __builtin_amdgcn_exp2f(st[g][2 * i]));
                    uint ub = __builtin_bit_cast(uint, __builtin_amdgcn_exp2f(st[g][2 * i + 1]));
                    uint r;
                    // r = (ua>>16) | (ub & 0xffff0000) — truncated bf16 pair
                    asm("v_perm_b32 %0, %1, %2, %3" : "=v"(r) : "v"(ub), "v"(ua), "v"(psel));
                    dd[g][i] = r;
                }

#pragma unroll
            for (int s = 0; s < 2; ++s) {
                const int step = ms * 2 + s;   // 0..7 -> V^T col block
                bf16x8 va0 = *(const bf16x8*)&Vs[p][l31][step * 16 + lhi * 8];
                bf16x8 va1 = *(const bf16x8*)&Vs[p][32 + l31][step * 16 + lhi * 8];
#pragma unroll
                for (int g = 0; g < 2; ++g) {
                    // == v_permlane32_swap_b32 semantics (Dst.row1 <-> Src.row0)
                    uint a0 = dd[g][4 * s + 0], a2 = dd[g][4 * s + 2];
                    uint a1 = dd[g][4 * s + 1], a3 = dd[g][4 * s + 3];
                    asm("v_permlane32_swap_b32 %0, %1" : "+v"(a0), "+v"(a2));
                    asm("v_permlane32_swap_b32 %0, %1" : "+v"(a1), "+v"(a3));
                    union { uint u[4]; bf16x8 v; } B;
                    B.u[0] = a0; B.u[1] = a1; B.u[2] = a2; B.u[3] = a3;
                    __builtin_amdgcn_s_setprio(1);
                    accO[g][0] = __builtin_amdgcn_mfma_f32_32x32x16_bf16(va0, B.v, accO[g][0], 0, 0, 0);
                    accO[g][1] = __builtin_amdgcn_mfma_f32_32x32x16_bf16(va1, B.v, accO[g][1], 0, 0, 0);
                    accL[g]    = __builtin_amdgcn_mfma_f32_32x32x16_bf16(ONE.v, B.v, accL[g], 0, 0, 0);
                    __builtin_amdgcn_s_setprio(0);
                }
            }
        }

        // write prefetched tile into the other buffer; one barrier per kt.
        if (pf) {
            *(uint4*)&Ks[p ^ 1][sr][sc] = kv0;       *(uint4*)&Ks[p ^ 1][sr][sc + 8] = kv1;
            *(uint4*)&Ks[p ^ 1][64 + sr][sc] = kv2;  *(uint4*)&Ks[p ^ 1][64 + sr][sc + 8] = kv3;
            *(uint4*)&Vs[p ^ 1][sr][sc] = vv0;       *(uint4*)&Vs[p ^ 1][sr][sc + 8] = vv1;
            *(uint4*)&Vs[p ^ 1][sr][64 + sc] = vv2;  *(uint4*)&Vs[p ^ 1][sr][64 + sc + 8] = vv3;
        }
        __syncthreads();
        p ^= 1;
    }

    // accL[g][r] == l[qrow] for every r — no reduction needed.
    if (NSLICE == 1) {
#pragma unroll
        for (int g = 0; g < 2; ++g) {
            const float inv = 1.0f / accL[g][0];
#pragma unroll
            for (int hf = 0; hf < 2; ++hf)
#pragma unroll
                for (int r = 0; r < 16; ++r) {
                    const int d = (r & 3) + 8 * (r >> 2) + 4 * lhi + 32 * hf;
                    AO[((size_t)(b * NSEQ + tok0 + g * 32)) * 512 + h * 64 + d] =
                        (ushort_t)f2bf(accO[g][hf][r] * inv);
                }
        }
    } else {
        if (lane < 32) {
#pragma unroll
            for (int g = 0; g < 2; ++g)
                Lp[(size_t)slice * 65536 + bh * 2048 + tok0 + g * 32] = accL[g][0];
        }
        ushort_t* Os = Op + (size_t)slice * 4194304;
#pragma unroll
        for (int g = 0; g < 2; ++g)
#pragma unroll
            for (int hf = 0; hf < 2; ++hf)
#pragma unroll
                for (int r = 0; r < 16; ++r) {
                    const int d = (r & 3) + 8 * (r >> 2) + 4 * lhi + 32 * hf;
                    Os[((size_t)(bh * 64 + d)) * 2048 + tok0 + g * 32] =
                        (ushort_t)f2bf(accO[g][hf][r]);
                }
    }
}

// ---------------------------------------------------------------------------
// Combine 2 split-K bf16 partials: AO[tok][e] = sum_s O_s / sum_s l_s.
// ---------------------------------------------------------------------------
__global__ __launch_bounds__(256)
void combine2Tb(const ushort_t* __restrict__ Op, const float* __restrict__ Lp,
                ushort_t* __restrict__ AO) {
    __shared__ float T[64][68];
    const int tid = threadIdx.x;
    const int tc = blockIdx.x, bh = blockIdx.y;
    const int b = bh >> 3, h = bh & 7;
    const int tok0 = tc * 64;

    const int d = tid >> 2, ts = (tid & 3) * 16;
    float acc[16];
#pragma unroll
    for (int i = 0; i < 16; ++i) acc[i] = 0.f;
#pragma unroll
    for (int s = 0; s < 2; ++s) {
        const ushort_t* P = Op + (size_t)s * 4194304
                               + ((size_t)(bh * 64 + d)) * 2048 + tok0 + ts;
#pragma unroll
        for (int k2 = 0; k2 < 2; ++k2) {
            uint4 u = *(const uint4*)(P + 8 * k2);
#pragma unroll
            for (int j = 0; j < 4; ++j) {
                uint uw = ((const uint*)&u)[j];
                acc[k2 * 8 + 2 * j]     += __builtin_bit_cast(float, uw << 16);
                acc[k2 * 8 + 2 * j + 1] += __builtin_bit_cast(float, uw & 0xffff0000u);
            }
        }
    }
#pragma unroll
    for (int k = 0; k < 4; ++k)
        *(f32x4*)&T[d][ts + 4 * k] = *(const f32x4*)&acc[4 * k];
    __syncthreads();

    const int tk = tid >> 2, ds = (tid & 3) * 16;
    const int tok = tok0 + tk;
    const float inv = 1.0f / (Lp[bh * 2048 + tok] + Lp[65536 + bh * 2048 + tok]);
    uint o[8];
#pragma unroll
    for (int k = 0; k < 8; ++k) {
        float a = T[ds + 2 * k][tk] * inv;
        float c = T[ds + 2 * k + 1][tk] * inv;
        o[k] = f2bf(a) | (f2bf(c) << 16);
    }
    ushort_t* dst = AO + ((size_t)(b * NSEQ + tok)) * 512 + h * 64 + ds;
    *(uint4*)dst       = *(const uint4*)&o[0];
    *(uint4*)(dst + 8) = *(const uint4*)&o[4];
}

// ---------------------------------------------------------------------------
extern "C" void kernel_launch(void* const* d_in, const int* in_sizes, int n_in,
                              void* d_out, int out_size, void* d_ws, size_t ws_size,
                              hipStream_t stream) {
    const float* x  = (const float*)d_in[0];
    const float* Wq = (const float*)d_in[1];
    const float* bq = (const float*)d_in[2];
    const float* Wk = (const float*)d_in[3];
    const float* bk = (const float*)d_in[4];
    const float* Wv = (const float*)d_in[5];
    const float* bv = (const float*)d_in[6];
    const float* Wo = (const float*)d_in[7];
    const float* bo = (const float*)d_in[8];

    char* ws = (char*)d_ws;
    ushort_t* xb    = (ushort_t*)(ws);                       //  8,388,608 B
    ushort_t* Wqkvb = (ushort_t*)(ws + 8388608);             //  1,572,864 B
    ushort_t* Wob   = (ushort_t*)(ws + 9961472);             //    524,288 B
    float*    bqkv  = (float*)   (ws + 10485760);            //      6,144 B
    ushort_t* QKb   = (ushort_t*)(ws + 10491904);            // 16,777,216 B
    ushort_t* VTg   = (ushort_t*)(ws + 27269120);            //  8,388,608 B
    ushort_t* AOb   = (ushort_t*)(ws + 35657728);            //  8,388,608 B
    ushort_t* Opart = (ushort_t*)(ws + 44046336);            // 16,777,216 B (2 slices bf16)
    float*    Lpart = (float*)   (ws);                       //    524,288 B overlay on xb
                                                             //  (xb dead after gemm<0>)
    const bool split = ws_size >= 78125056;

    prep<<<4096, 256, 0, stream>>>(x, Wq, Wk, Wv, Wo, bq, bk, bv,
                                   xb, Wqkvb, bqkv, Wob);
    gemm64<0><<<dim3(128, 24), 256, 0, stream>>>(xb, Wqkvb, bqkv, QKb, VTg, nullptr);
    if (split) {
        attn_mfma<2><<<dim3(8, 32, 2), 256, 0, stream>>>(QKb, VTg, Opart, Lpart, nullptr);
        combine2Tb<<<dim3(32, 32), 256, 0, stream>>>(Opart, Lpart, AOb);
    } else {
        attn_mfma<1><<<dim3(8, 32, 1), 256, 0, stream>>>(QKb, VTg, nullptr, nullptr, AOb);
    }
    gemm64<1><<<dim3(128, 8), 256, 0, stream>>>(AOb, Wob, bo, nullptr, nullptr, (float*)d_out);
}

// Round 11
// 164.698 us; speedup vs baseline: 1.0833x; 1.0168x over previous
//
#include <hip/hip_runtime.h>

typedef float f32x4 __attribute__((ext_vector_type(4)));
typedef float f32x16 __attribute__((ext_vector_type(16)));
typedef short bf16x8 __attribute__((ext_vector_type(8)));
typedef unsigned int uint;
typedef unsigned short ushort_t;

#define EMB    512
#define NSEQ   2048
#define NBATCH 4
#define NHEAD  8
#define MROWS  (NBATCH * NSEQ)   // 8192
#define CEXP   0.06375872f       // log2(e) / sqrt(512)

// round-to-nearest-even fp32 -> bf16 (bit trick)
__device__ __forceinline__ uint f2bf(float x) {
    uint u = __builtin_bit_cast(uint, x);
    return (u + 0x7fffu + ((u >> 16) & 1u)) >> 16;
}

// async global->LDS, 16B per lane; LDS dest = wave-uniform base + lane*16
__device__ __forceinline__ void glds16(const void* g, void* l) {
    __builtin_amdgcn_global_load_lds(
        (const __attribute__((address_space(1))) uint*)g,
        (__attribute__((address_space(3))) uint*)l, 16, 0, 0);
}

// ---------------------------------------------------------------------------
// Prep: x -> bf16; Wq|Wk|Wv -> Wqkvb bf16 [1536][512]; biases concat; Wo -> bf16
// ---------------------------------------------------------------------------
__global__ __launch_bounds__(256)
void prep(const float* __restrict__ x,
          const float* __restrict__ Wq, const float* __restrict__ Wk,
          const float* __restrict__ Wv, const float* __restrict__ Wo,
          const float* __restrict__ bq, const float* __restrict__ bk,
          const float* __restrict__ bv,
          ushort_t* __restrict__ xb, ushort_t* __restrict__ Wqkvb,
          float* __restrict__ bqkv, ushort_t* __restrict__ Wob) {
    int t = blockIdx.x * 256 + threadIdx.x;   // f4-group index, 1048576 total
    {
        float4 v = ((const float4*)x)[t];
        uint2 p;
        p.x = f2bf(v.x) | (f2bf(v.y) << 16);
        p.y = f2bf(v.z) | (f2bf(v.w) << 16);
        ((uint2*)xb)[t] = p;
    }
    if (t < 65536) {   // 512*512/4 groups per weight
        float4 a = ((const float4*)Wq)[t];
        float4 b = ((const float4*)Wk)[t];
        float4 c = ((const float4*)Wv)[t];
        float4 d = ((const float4*)Wo)[t];
        uint2 p;
        p.x = f2bf(a.x) | (f2bf(a.y) << 16); p.y = f2bf(a.z) | (f2bf(a.w) << 16);
        ((uint2*)Wqkvb)[t] = p;
        p.x = f2bf(b.x) | (f2bf(b.y) << 16); p.y = f2bf(b.z) | (f2bf(b.w) << 16);
        ((uint2*)Wqkvb)[t + 65536] = p;
        p.x = f2bf(c.x) | (f2bf(c.y) << 16); p.y = f2bf(c.z) | (f2bf(c.w) << 16);
        ((uint2*)Wqkvb)[t + 131072] = p;
        p.x = f2bf(d.x) | (f2bf(d.y) << 16); p.y = f2bf(d.z) | (f2bf(d.w) << 16);
        ((uint2*)Wob)[t] = p;
    }
    if (t < 512) {
        bqkv[t] = bq[t]; bqkv[512 + t] = bk[t]; bqkv[1024 + t] = bv[t];
    }
}

// ---------------------------------------------------------------------------
// GEMM C[8192 x N] = A[8192x512]bf16 * BT[Nx512]bf16 + bias, 64x64 tile,
// R15 2-phase double-buffered K-loop. V-epilogue via LDS transpose ->
// 128B coalesced runs. MODE 0: QKV (N=1536); MODE 1: out proj (N=512).
// ---------------------------------------------------------------------------
template<int MODE>
__global__ __launch_bounds__(256)
void gemm64(const ushort_t* __restrict__ A, const ushort_t* __restrict__ BT,
            const float* __restrict__ bias, ushort_t* __restrict__ oQK,
            ushort_t* __restrict__ oVT, float* __restrict__ oC) {
    __shared__ __align__(16) char smem[32768];
    ushort_t (*As)[2][64][32] = (ushort_t (*)[2][64][32])smem;           // 16KB
    ushort_t (*Bs)[2][64][32] = (ushort_t (*)[2][64][32])(smem + 16384); // 16KB
    float (*ep)[68] = (float (*)[68])smem;    // Q/K + MODE1 epilogue overlay
    float (*epV)[69] = (float (*)[69])smem;   // V epilogue overlay (64x69 fp32)

    const int tid = threadIdx.x, wave = tid >> 6, lane = tid & 63;
    const int m0 = blockIdx.x * 64, n0 = blockIdx.y * 64;
    const int wr = (wave & 1) * 32, wc = (wave >> 1) * 32;

    f32x4 acc[2][2];
#pragma unroll
    for (int i = 0; i < 2; ++i)
#pragma unroll
        for (int j = 0; j < 2; ++j) acc[i][j] = (f32x4){0.f, 0.f, 0.f, 0.f};

    // per-lane global source: row = wave*16 + lane/4, col-seg = (lane&3)*16B
    const int grow = wave * 16 + (lane >> 2);
    const int gcol = (lane & 3) * 8;
    const ushort_t* Ag = A  + (size_t)(m0 + grow) * 512 + gcol;
    const ushort_t* Bg = BT + (size_t)(n0 + grow) * 512 + gcol;
    const int fr = lane & 15, fc = (lane >> 4) * 8;

    // prologue: stage kt=0 into buffer 0
#pragma unroll
    for (int t = 0; t < 2; ++t) {
        glds16(Ag + t * 32, &As[0][t][wave * 16][0]);
        glds16(Bg + t * 32, &Bs[0][t][wave * 16][0]);
    }
    __syncthreads();   // vmcnt(0) drained -> buffer 0 visible

    int p = 0;
    for (int kt = 0; kt < 8; ++kt) {
        // issue next-tile prefetch FIRST — latency hides under this kt's MFMA
        if (kt < 7) {
#pragma unroll
            for (int t = 0; t < 2; ++t) {
                glds16(Ag + (kt + 1) * 64 + t * 32, &As[p ^ 1][t][wave * 16][0]);
                glds16(Bg + (kt + 1) * 64 + t * 32, &Bs[p ^ 1][t][wave * 16][0]);
            }
        }
#pragma unroll
        for (int t = 0; t < 2; ++t) {
            bf16x8 af[2], bf[2];
#pragma unroll
            for (int i = 0; i < 2; ++i) af[i] = *(const bf16x8*)&As[p][t][wr + i * 16 + fr][fc];
#pragma unroll
            for (int j = 0; j < 2; ++j) bf[j] = *(const bf16x8*)&Bs[p][t][wc + j * 16 + fr][fc];
#pragma unroll
            for (int i = 0; i < 2; ++i)
#pragma unroll
                for (int j = 0; j < 2; ++j)
                    acc[i][j] = __builtin_amdgcn_mfma_f32_16x16x32_bf16(af[i], bf[j], acc[i][j], 0, 0, 0);
        }
        __syncthreads();   // drains prefetch (vmcnt 0) + guards buffer reuse
        p ^= 1;
    }

    const int col_l = lane & 15, row_l = (lane >> 4) * 4;

    if (MODE == 0 && n0 >= 1024) {
        // V part: LDS-transposed coalesced bf16 stores
        const int e0 = n0 - 1024;
#pragma unroll
        for (int j = 0; j < 2; ++j) {
            const float bvv = bias[n0 + wc + j * 16 + col_l];
#pragma unroll
            for (int i = 0; i < 2; ++i) {
                f32x4 v = acc[i][j];
#pragma unroll
                for (int r = 0; r < 4; ++r)
                    epV[wc + j * 16 + col_l][wr + i * 16 + row_l + r] = v[r] + bvv;
            }
        }
        __syncthreads();
        const int e = tid >> 2, ts = (tid & 3) * 16;
        const int bb = m0 >> 11, tok = (m0 & 2047) + ts;
        uint o[8];
#pragma unroll
        for (int k = 0; k < 8; ++k)
            o[k] = f2bf(epV[e][ts + 2 * k]) | (f2bf(epV[e][ts + 2 * k + 1]) << 16);
        ushort_t* dst = &oVT[((size_t)(bb * 512 + e0 + e)) * 2048 + tok];
        *(uint4*)dst       = *(const uint4*)&o[0];
        *(uint4*)(dst + 8) = *(const uint4*)&o[4];
        return;
    }

    // LDS-transposed coalesced epilogue (QK bf16 / out-proj fp32); ep overlays tiles
    const float scale = (MODE == 0 && n0 < 512) ? CEXP : 1.0f;
    float bv[2];
#pragma unroll
    for (int j = 0; j < 2; ++j) bv[j] = bias[n0 + wc + j * 16 + col_l];

    const int erow = tid >> 3, eseg = (tid & 7) * 8;
#pragma unroll
    for (int c = 0; c < 2; ++c) {
        __syncthreads();
        if (wr == c * 32) {
#pragma unroll
            for (int i = 0; i < 2; ++i) {
#pragma unroll
                for (int j = 0; j < 2; ++j) {
                    f32x4 v = acc[i][j];
#pragma unroll
                    for (int r = 0; r < 4; ++r)
                        ep[i * 16 + row_l + r][wc + j * 16 + col_l] = (v[r] + bv[j]) * scale;
                }
            }
        }
        __syncthreads();
        const int grow2 = m0 + c * 32 + erow;
        if (MODE == 0) {
            uint4 o0;
#pragma unroll
            for (int k = 0; k < 4; ++k) {
                ((uint*)&o0)[k] = f2bf(ep[erow][eseg + k * 2])
                                | (f2bf(ep[erow][eseg + k * 2 + 1]) << 16);
            }
            *(uint4*)&oQK[(size_t)grow2 * 1024 + n0 + eseg] = o0;
        } else {
#pragma unroll
            for (int k = 0; k < 2; ++k) {
                f32x4 v = *(const f32x4*)&ep[erow][eseg + k * 4];
                *(f32x4*)&oC[(size_t)grow2 * 512 + n0 + eseg + k * 4] = v;
            }
        }
    }
}

// ---------------------------------------------------------------------------
// MFMA flash attention, O^T formulation; 64 q-rows per wave (two 32-row
// groups sharing ka/va LDS fragment reads). KVBLK=64 (R17's 128 regressed:
// +64 staging VGPRs live across compute cost more than 16 saved barriers).
// R18: XCD-AWARE BLOCK SWIZZLE (T1). All 512 blocks are co-resident
// (2/CU x 256 CU); the 8 qt-blocks sharing a (bh,slice) K/V slice (256 KB)
// previously round-robined across the 8 non-coherent XCD L2s (FETCH 69.7 MB
// vs ~25 MB unique). 1D launch + bijective decode places all 8 group
// members on ONE XCD (wgid%8 = XCD heuristic): 8 groups x 256 KB = 2 MB
// <= 4 MB L2/XCD. Pure index permutation — bit-identical output.
// ---------------------------------------------------------------------------
template<int NSLICE>
__global__ __launch_bounds__(256, 2)
void attn_mfma(const ushort_t* __restrict__ QK, const ushort_t* __restrict__ VT,
               ushort_t* __restrict__ Op, float* __restrict__ Lp,
               ushort_t* __restrict__ AO) {
    __shared__ ushort_t Ks[2][64][72];    // [buf][krow][d]
    __shared__ ushort_t Vs[2][64][72];    // [buf][d][krow]  (V^T tile)

    const int tid = threadIdx.x, w = tid >> 6, lane = tid & 63;
    int qt, bh, slice;
    if (NSLICE == 2) {
        // XCD swizzle: group g=(bh,slice) -> XCD g&7; member m = qt.
        // forward: wgid = (g&7) | (m<<3) | ((g>>3)<<6); decode is its inverse.
        const int wgid = blockIdx.x;              // grid = 512 x 1 x 1
        const int g = (wgid & 7) | ((wgid >> 6) << 3);
        qt = (wgid >> 3) & 7;
        bh = g & 31;
        slice = g >> 5;
    } else {
        qt = blockIdx.x; bh = blockIdx.y; slice = 0;
    }
    const int b = bh >> 3, h = bh & 7;
    const int l31 = lane & 31, lhi = lane >> 5;

    const int tok0 = qt * 256 + w * 64 + l31;   // q-group g adds g*32
    bf16x8 qf[2][4];
#pragma unroll
    for (int g = 0; g < 2; ++g)
#pragma unroll
        for (int ks = 0; ks < 4; ++ks)
            qf[g][ks] = *(const bf16x8*)&QK[(size_t)(b * NSEQ + tok0 + g * 32) * 1024
                                            + h * 64 + ks * 16 + lhi * 8];

    f32x16 accO[2][2];   // [g][d-half]
    f32x16 accL[2];      // [g] row-sum accumulator (ones-MFMA)
#pragma unroll
    for (int g = 0; g < 2; ++g) {
#pragma unroll
        for (int i = 0; i < 16; ++i) { accO[g][0][i] = 0.f; accO[g][1][i] = 0.f; accL[g][i] = 0.f; }
    }
    union { uint u[4]; bf16x8 v; } ONE;
    ONE.u[0] = 0x3f803f80u; ONE.u[1] = 0x3f803f80u;
    ONE.u[2] = 0x3f803f80u; ONE.u[3] = 0x3f803f80u;

    const int sr = tid & 63, sc = (tid >> 6) * 16;
    const ushort_t* Kg = QK + (size_t)(b * NSEQ) * 1024 + 512 + h * 64;
    const ushort_t* Vg = VT + ((size_t)(b * 512 + h * 64)) * 2048;

    const int kt0 = slice * (32 / NSLICE), kt1 = kt0 + 32 / NSLICE;

    // prologue: stage tile kt0 into buffer 0
    {
        const int k0 = kt0 * 64;
        uint4 kv0 = *(const uint4*)&Kg[(size_t)(k0 + sr) * 1024 + sc];
        uint4 kv1 = *(const uint4*)&Kg[(size_t)(k0 + sr) * 1024 + sc + 8];
        uint4 vv0 = *(const uint4*)&Vg[(size_t)sr * 2048 + k0 + sc];
        uint4 vv1 = *(const uint4*)&Vg[(size_t)sr * 2048 + k0 + sc + 8];
        *(uint4*)&Ks[0][sr][sc] = kv0;  *(uint4*)&Ks[0][sr][sc + 8] = kv1;
        *(uint4*)&Vs[0][sr][sc] = vv0;  *(uint4*)&Vs[0][sr][sc + 8] = vv1;
        __syncthreads();
    }

    const uint psel = 0x07060302u;   // v_perm selector: {ua.b2,ua.b3,ub.b2,ub.b3}
    int p = 0;
#pragma unroll 2
    for (int kt = kt0; kt < kt1; ++kt) {
        // issue next-tile global loads FIRST — latency hides under compute
        uint4 kv0, kv1, vv0, vv1;
        const bool pf = (kt + 1 < kt1);
        if (pf) {
            const int k0 = (kt + 1) * 64;
            kv0 = *(const uint4*)&Kg[(size_t)(k0 + sr) * 1024 + sc];
            kv1 = *(const uint4*)&Kg[(size_t)(k0 + sr) * 1024 + sc + 8];
            vv0 = *(const uint4*)&Vg[(size_t)sr * 2048 + k0 + sc];
            vv1 = *(const uint4*)&Vg[(size_t)sr * 2048 + k0 + sc + 8];
        }

        // compute from buffer p
#pragma unroll
        for (int ms = 0; ms < 2; ++ms) {   // krow halves 0..31 / 32..63
            bf16x8 ka[4];
#pragma unroll
            for (int ks = 0; ks < 4; ++ks)
                ka[ks] = *(const bf16x8*)&Ks[p][ms * 32 + l31][ks * 16 + lhi * 8];

            f32x16 st[2];
#pragma unroll
            for (int g = 0; g < 2; ++g)
#pragma unroll
                for (int i = 0; i < 16; ++i) st[g][i] = 0.f;
            __builtin_amdgcn_s_setprio(1);
#pragma unroll
            for (int ks = 0; ks < 4; ++ks) {
                st[0] = __builtin_amdgcn_mfma_f32_32x32x16_bf16(ka[ks], qf[0][ks], st[0], 0, 0, 0);
                st[1] = __builtin_amdgcn_mfma_f32_32x32x16_bf16(ka[ks], qf[1][ks], st[1], 0, 0, 0);
            }
            __builtin_amdgcn_s_setprio(0);

            uint dd[2][8];
#pragma unroll
            for (int g = 0; g < 2; ++g)
#pragma unroll
                for (int i = 0; i < 8; ++i) {
                    uint ua = __builtin_bit_cast(uint, __builtin_amdgcn_exp2f(st[g][2 * i]));
                    uint ub = __builtin_bit_cast(uint, __builtin_amdgcn_exp2f(st[g][2 * i + 1]));
                    uint r;
                    // r = (ua>>16) | (ub & 0xffff0000) — truncated bf16 pair
                    asm("v_perm_b32 %0, %1, %2, %3" : "=v"(r) : "v"(ub), "v"(ua), "v"(psel));
                    dd[g][i] = r;
                }

#pragma unroll
            for (int s = 0; s < 2; ++s) {
                const int step = ms * 2 + s;
                bf16x8 va0 = *(const bf16x8*)&Vs[p][l31][step * 16 + lhi * 8];
                bf16x8 va1 = *(const bf16x8*)&Vs[p][32 + l31][step * 16 + lhi * 8];
#pragma unroll
                for (int g = 0; g < 2; ++g) {
                    // == v_permlane32_swap_b32 semantics (Dst.row1 <-> Src.row0)
                    uint a0 = dd[g][4 * s + 0], a2 = dd[g][4 * s + 2];
                    uint a1 = dd[g][4 * s + 1], a3 = dd[g][4 * s + 3];
                    asm("v_permlane32_swap_b32 %0, %1" : "+v"(a0), "+v"(a2));
                    asm("v_permlane32_swap_b32 %0, %1" : "+v"(a1), "+v"(a3));
                    union { uint u[4]; bf16x8 v; } B;
                    B.u[0] = a0; B.u[1] = a1; B.u[2] = a2; B.u[3] = a3;
                    __builtin_amdgcn_s_setprio(1);
                    accO[g][0] = __builtin_amdgcn_mfma_f32_32x32x16_bf16(va0, B.v, accO[g][0], 0, 0, 0);
                    accO[g][1] = __builtin_amdgcn_mfma_f32_32x32x16_bf16(va1, B.v, accO[g][1], 0, 0, 0);
                    accL[g]    = __builtin_amdgcn_mfma_f32_32x32x16_bf16(ONE.v, B.v, accL[g], 0, 0, 0);
                    __builtin_amdgcn_s_setprio(0);
                }
            }
        }

        // write prefetched tile into the other buffer; one barrier per kt.
        if (pf) {
            *(uint4*)&Ks[p ^ 1][sr][sc] = kv0;  *(uint4*)&Ks[p ^ 1][sr][sc + 8] = kv1;
            *(uint4*)&Vs[p ^ 1][sr][sc] = vv0;  *(uint4*)&Vs[p ^ 1][sr][sc + 8] = vv1;
        }
        __syncthreads();
        p ^= 1;
    }

    // accL[g][r] == l[qrow] for every r — no reduction needed.
    if (NSLICE == 1) {
#pragma unroll
        for (int g = 0; g < 2; ++g) {
            const float inv = 1.0f / accL[g][0];
#pragma unroll
            for (int hf = 0; hf < 2; ++hf)
#pragma unroll
                for (int r = 0; r < 16; ++r) {
                    const int d = (r & 3) + 8 * (r >> 2) + 4 * lhi + 32 * hf;
                    AO[((size_t)(b * NSEQ + tok0 + g * 32)) * 512 + h * 64 + d] =
                        (ushort_t)f2bf(accO[g][hf][r] * inv);
                }
        }
    } else {
        if (lane < 32) {
#pragma unroll
            for (int g = 0; g < 2; ++g)
                Lp[(size_t)slice * 65536 + bh * 2048 + tok0 + g * 32] = accL[g][0];
        }
        ushort_t* Os = Op + (size_t)slice * 4194304;
#pragma unroll
        for (int g = 0; g < 2; ++g)
#pragma unroll
            for (int hf = 0; hf < 2; ++hf)
#pragma unroll
                for (int r = 0; r < 16; ++r) {
                    const int d = (r & 3) + 8 * (r >> 2) + 4 * lhi + 32 * hf;
                    Os[((size_t)(bh * 64 + d)) * 2048 + tok0 + g * 32] =
                        (ushort_t)f2bf(accO[g][hf][r]);
                }
    }
}

// ---------------------------------------------------------------------------
// Combine 2 split-K bf16 partials: AO[tok][e] = sum_s O_s / sum_s l_s.
// ---------------------------------------------------------------------------
__global__ __launch_bounds__(256)
void combine2Tb(const ushort_t* __restrict__ Op, const float* __restrict__ Lp,
                ushort_t* __restrict__ AO) {
    __shared__ float T[64][68];
    const int tid = threadIdx.x;
    const int tc = blockIdx.x, bh = blockIdx.y;
    const int b = bh >> 3, h = bh & 7;
    const int tok0 = tc * 64;

    const int d = tid >> 2, ts = (tid & 3) * 16;
    float acc[16];
#pragma unroll
    for (int i = 0; i < 16; ++i) acc[i] = 0.f;
#pragma unroll
    for (int s = 0; s < 2; ++s) {
        const ushort_t* P = Op + (size_t)s * 4194304
                               + ((size_t)(bh * 64 + d)) * 2048 + tok0 + ts;
#pragma unroll
        for (int k2 = 0; k2 < 2; ++k2) {
            uint4 u = *(const uint4*)(P + 8 * k2);
#pragma unroll
            for (int j = 0; j < 4; ++j) {
                uint uw = ((const uint*)&u)[j];
                acc[k2 * 8 + 2 * j]     += __builtin_bit_cast(float, uw << 16);
                acc[k2 * 8 + 2 * j + 1] += __builtin_bit_cast(float, uw & 0xffff0000u);
            }
        }
    }
#pragma unroll
    for (int k = 0; k < 4; ++k)
        *(f32x4*)&T[d][ts + 4 * k] = *(const f32x4*)&acc[4 * k];
    __syncthreads();

    const int tk = tid >> 2, ds = (tid & 3) * 16;
    const int tok = tok0 + tk;
    const float inv = 1.0f / (Lp[bh * 2048 + tok] + Lp[65536 + bh * 2048 + tok]);
    uint o[8];
#pragma unroll
    for (int k = 0; k < 8; ++k) {
        float a = T[ds + 2 * k][tk] * inv;
        float c = T[ds + 2 * k + 1][tk] * inv;
        o[k] = f2bf(a) | (f2bf(c) << 16);
    }
    ushort_t* dst = AO + ((size_t)(b * NSEQ + tok)) * 512 + h * 64 + ds;
    *(uint4*)dst       = *(const uint4*)&o[0];
    *(uint4*)(dst + 8) = *(const uint4*)&o[4];
}

// ---------------------------------------------------------------------------
extern "C" void kernel_launch(void* const* d_in, const int* in_sizes, int n_in,
                              void* d_out, int out_size, void* d_ws, size_t ws_size,
                              hipStream_t stream) {
    const float* x  = (const float*)d_in[0];
    const float* Wq = (const float*)d_in[1];
    const float* bq = (const float*)d_in[2];
    const float* Wk = (const float*)d_in[3];
    const float* bk = (const float*)d_in[4];
    const float* Wv = (const float*)d_in[5];
    const float* bv = (const float*)d_in[6];
    const float* Wo = (const float*)d_in[7];
    const float* bo = (const float*)d_in[8];

    char* ws = (char*)d_ws;
    ushort_t* xb    = (ushort_t*)(ws);                       //  8,388,608 B
    ushort_t* Wqkvb = (ushort_t*)(ws + 8388608);             //  1,572,864 B
    ushort_t* Wob   = (ushort_t*)(ws + 9961472);             //    524,288 B
    float*    bqkv  = (float*)   (ws + 10485760);            //      6,144 B
    ushort_t* QKb   = (ushort_t*)(ws + 10491904);            // 16,777,216 B
    ushort_t* VTg   = (ushort_t*)(ws + 27269120);            //  8,388,608 B
    ushort_t* AOb   = (ushort_t*)(ws + 35657728);            //  8,388,608 B
    ushort_t* Opart = (ushort_t*)(ws + 44046336);            // 16,777,216 B (2 slices bf16)
    float*    Lpart = (float*)   (ws);                       //    524,288 B overlay on xb
                                                             //  (xb dead after gemm<0>)
    const bool split = ws_size >= 78125056;

    prep<<<4096, 256, 0, stream>>>(x, Wq, Wk, Wv, Wo, bq, bk, bv,
                                   xb, Wqkvb, bqkv, Wob);
    gemm64<0><<<dim3(128, 24), 256, 0, stream>>>(xb, Wqkvb, bqkv, QKb, VTg, nullptr);
    if (split) {
        attn_mfma<2><<<dim3(512), 256, 0, stream>>>(QKb, VTg, Opart, Lpart, nullptr);
        combine2Tb<<<dim3(32, 32), 256, 0, stream>>>(Opart, Lpart, AOb);
    } else {
        attn_mfma<1><<<dim3(8, 32), 256, 0, stream>>>(QKb, VTg, nullptr, nullptr, AOb);
    }
    gemm64<1><<<dim3(128, 8), 256, 0, stream>>>(AOb, Wob, bo, nullptr, nullptr, (float*)d_out);
}